// Round 6
// baseline (391.228 us; speedup 1.0000x reference)
//
#include <hip/hip_runtime.h>

// LSTMP via MFMA, fp32 I/O, f16 compute, fp32 accumulate.
// B=4096, T=512, IN=4, HID=64, PROJ=52. Grid 256 x 512thr (8 waves, 2/SIMD),
// 16 batch/block.
//
// Round-18: TWO-STREAM SOFTWARE PIPELINE. R13/R15/R16 nulls proved the step
// is one serialized dependency chain per barrier interval (read -> MFMA ->
// trans -> write); co-resident lockstepped waves can't fill each other's
// stalls, and within one stream there is no independent work to slide into
// the read/MFMA window. Fix by DATAFLOW: split batches into stream s0
// (b0-7) and s1 (b8-15), phase-offset by half a step:
//   phase B(t): {read d_s1 + 6 MFMA s1(t)}  ||  {trans s0(t) -> write d_s0(t)}
//   phase A(t+1): {read d_s0 + 6 MFMA s0(t+1)} || {trans s1(t) -> write d_s1(t)}
// The trans block consumes REGISTERS from the previous phase - fully
// independent of this phase's loads/MFMAs - so it issues under the ds_read
// latency and MFMA chain. 2 barriers/step; each protects one stream's
// write->read; streams use disjoint d rows (0-7 / 8-15) -> SINGLE d buffer.
// B-frag cols 8-15 mirror cols 0-7 (same 8 batches), so lane col>=8 simply
// selects tile1's accumulator: no swizzle repack, 1 cell/lane/stream,
// trans issue per SIMD conserved (40/step). MFMA/wave/step doubles to 12
// (matrix pipe was 16% busy - free).
// Per-cell gate packing as R16: tile row = 4*hloc+gate; lane's f32x4 acc =
// [i,f,g,o] of one cell. Per-output accumulate order (xb seed, M0, M1),
// scales and f16 RTNE identical to R12/R13/R16 -> absmax exactly
// 9.765625e-4.
//   gates = (Whh@Whr)@d + [Wih|b]@[x;1]   (M precomputed per block, fp32)
// x staged to LDS as f16 once; log2e folded (i,f,o rows xL; g rows x2L;
// c' = 2L*c); h only in epilogue (Whr@d_T).

#define T_STEPS 512
#define HID 64
#define NPROJ 52
#define NBATCH 16
#define ROWB 136
#define DBYTES (NBATCH * ROWB)     // 2176 B, single buffer (rows=batch)
#define XBYTES (T_STEPS * 128)     // 65536 B: x_lds[t][b] 8B cells (4 x f16)
#define LOG2E 1.44269504088896340736f

typedef _Float16 half8 __attribute__((ext_vector_type(8)));
typedef float f32x4 __attribute__((ext_vector_type(4)));

__device__ __forceinline__ float exp2_f(float x) {
#if __has_builtin(__builtin_amdgcn_exp2f)
    return __builtin_amdgcn_exp2f(x);
#else
    return exp2f(x);
#endif
}
__device__ __forceinline__ float rcp_f(float x) {
    return __builtin_amdgcn_rcpf(x);
}

__global__ __launch_bounds__(512, 2)
void lstmp_kernel(const float* __restrict__ x,      // [4096][512][4]
                  const float* __restrict__ Wih,    // [256][4]
                  const float* __restrict__ Whh,    // [256][52]
                  const float* __restrict__ bih,    // [256]
                  const float* __restrict__ bhh,    // [256]
                  const float* __restrict__ Whr,    // [52][64]
                  float* __restrict__ out)          // [4096][52]
{
    __shared__ char lds[XBYTES + DBYTES];
    char* xl = lds;                 // x_lds: [t][b] 8B cells
    char* dl = lds + XBYTES;        // single d buffer, [16 batch][136B]

    const int tid  = threadIdx.x;
    const int lane = tid & 63;
    const int wave = tid >> 6;           // 0..7, owns hid block [8w, 8w+8)
    const int quad = lane >> 4;
    const int col  = lane & 15;
    const int bloc = col & 7;            // batch-in-stream
    const bool hi  = (col & 8) != 0;     // lane uses tile1's acc

    // ---- zero d buffer (t=0 phases read zeros as d(-1)) ----
    {
        unsigned* p = (unsigned*)dl;
        for (int i = tid; i < (int)(DBYTES / 4); i += 512) p[i] = 0u;
    }

    // ---- stage x -> LDS as f16 (one-time; coalesced global reads) ----
    {
        const float4* xg = (const float4*)x + (size_t)blockIdx.x * NBATCH * T_STEPS;
        for (int i = tid; i < NBATCH * T_STEPS; i += 512) {
            const int b = i >> 9;          // global layout is b-major
            const int t = i & (T_STEPS - 1);
            const float4 v = xg[i];
            union { _Float16 h[4]; unsigned long long q; } u;
            u.h[0] = (_Float16)v.x; u.h[1] = (_Float16)v.y;
            u.h[2] = (_Float16)v.z; u.h[3] = (_Float16)v.w;
            *(unsigned long long*)(xl + t * 128 + b * 8) = u.q;
        }
    }

    // ---- A-frag rows: tile row r = 4*hloc + gate (per-cell interleave) ----
    const int gate = col & 3;
    const int hl   = col >> 2;
    int rowT[2];
    rowT[0] = gate * HID + wave * 8 + hl;   // tile0: hid 8w+hl
    rowT[1] = rowT[0] + 4;                  // tile1: hid 8w+4+hl

    // ---- one-time: M = Whh @ Whr for the 2 packed rows (fp32) ----
    float macc[2][16];
#pragma unroll
    for (int g = 0; g < 2; ++g)
#pragma unroll
        for (int kk = 0; kk < 16; ++kk) macc[g][kk] = 0.0f;

    for (int p = 0; p < NPROJ; ++p) {
        const float w0 = Whh[rowT[0] * NPROJ + p];
        const float w1 = Whh[rowT[1] * NPROJ + p];
        const float* wr = Whr + p * HID + quad * 8;
        const float4 r0 = *(const float4*)(wr);
        const float4 r1 = *(const float4*)(wr + 4);
        const float4 r2 = *(const float4*)(wr + 32);
        const float4 r3 = *(const float4*)(wr + 36);
        const float rk[16] = {r0.x, r0.y, r0.z, r0.w, r1.x, r1.y, r1.z, r1.w,
                              r2.x, r2.y, r2.z, r2.w, r3.x, r3.y, r3.z, r3.w};
#pragma unroll
        for (int kk = 0; kk < 16; ++kk) {
            macc[0][kk] = fmaf(w0, rk[kk], macc[0][kk]);
            macc[1][kk] = fmaf(w1, rk[kk], macc[1][kk]);
        }
    }

    // ---- fold log2e, convert to f16 A-frags ----
    const float sc = (gate == 2) ? (2.0f * LOG2E) : LOG2E;   // g rows x2L
    half8 aM[2][2];   // [tile][K-chunk] (shared by both streams)
    half8 aXB[2];     // [Wih | bias] part, K=32 (quad0: k<4 = x, k==4 = 1-col)
#pragma unroll
    for (int g = 0; g < 2; ++g) {
#pragma unroll
        for (int ch = 0; ch < 2; ++ch)
#pragma unroll
            for (int j = 0; j < 8; ++j)
                aM[g][ch][j] = (_Float16)(macc[g][ch * 8 + j] * sc);
#pragma unroll
        for (int j = 0; j < 8; ++j) {
            const int k = quad * 8 + j;
            float v = 0.0f;
            if (k < 4)       v = Wih[rowT[g] * 4 + k];
            else if (k == 4) v = bih[rowT[g]] + bhh[rowT[g]];
            aXB[g][j] = (_Float16)(v * sc);
        }
    }

    float caccS0 = 0.0f, caccS1 = 0.0f;   // c' = 2L*c, 1 cell/lane/stream

    // lane's cell: hid = 8w + quad + 4*hi, batch = stream_base + bloc
    const int myhid  = wave * 8 + quad + (hi ? 4 : 0);
    const int woffS0 = bloc * ROWB + myhid * 2;            // d_s0 write (b16)
    const int woffS1 = (8 + bloc) * ROWB + myhid * 2;      // d_s1 write
    const int drS0   = bloc * ROWB + quad * 16;            // d_s0 read base
    const int drS1   = (8 + bloc) * ROWB + quad * 16;      // d_s1 read base
    const char* xrd0 = xl + bloc * 8;                      // x, stream 0
    const char* xrd1 = xl + (8 + bloc) * 8;                // x, stream 1

    __syncthreads();   // staging + zeros visible

    const f32x4 z = {0.f, 0.f, 0.f, 0.f};
    f32x4 A0a, A0b, A1a, A1b;   // per-stream accs (tile0, tile1)

    // MFMA phase for one stream: reads x(tt) + d rows, 6 MFMA.
    auto MFMA_PH = [&](const char* xr, int dr, int tt, f32x4& Pa, f32x4& Pb) {
        union { unsigned long long q; _Float16 h[4]; } xu;
        xu.q = (quad == 0) ? *(const unsigned long long*)(xr + tt * 128) : 0ull;
        const char* p0 = dl + dr;
        union { unsigned long long q[2]; half8 h; } u0, u1;
        u0.q[0] = *(const unsigned long long*)(p0);
        u0.q[1] = *(const unsigned long long*)(p0 + 8);
        u1.q[0] = *(const unsigned long long*)(p0 + 64);
        u1.q[1] = *(const unsigned long long*)(p0 + 72);
        half8 bx;
#pragma unroll
        for (int j = 0; j < 8; ++j) bx[j] = (_Float16)0.0f;
        if (quad == 0) {
            bx[0] = xu.h[0]; bx[1] = xu.h[1]; bx[2] = xu.h[2]; bx[3] = xu.h[3];
            bx[4] = (_Float16)1.0f;
        }
        Pa = __builtin_amdgcn_mfma_f32_16x16x32_f16(aXB[0], bx, z, 0, 0, 0);
        Pb = __builtin_amdgcn_mfma_f32_16x16x32_f16(aXB[1], bx, z, 0, 0, 0);
        Pa = __builtin_amdgcn_mfma_f32_16x16x32_f16(aM[0][0], u0.h, Pa, 0, 0, 0);
        Pb = __builtin_amdgcn_mfma_f32_16x16x32_f16(aM[1][0], u0.h, Pb, 0, 0, 0);
        Pa = __builtin_amdgcn_mfma_f32_16x16x32_f16(aM[0][1], u1.h, Pa, 0, 0, 0);
        Pb = __builtin_amdgcn_mfma_f32_16x16x32_f16(aM[1][1], u1.h, Pb, 0, 0, 0);
    };

    // trans + d write for the OTHER stream (registers from previous phase).
    auto TRANS_WR = [&](const f32x4& Pa, const f32x4& Pb, float& cc, int woff) {
        const float g0 = hi ? Pb[0] : Pa[0];
        const float g1 = hi ? Pb[1] : Pa[1];
        const float g2 = hi ? Pb[2] : Pa[2];
        const float g3 = hi ? Pb[3] : Pa[3];
        const float iv = rcp_f(1.0f + exp2_f(-g0));                       // sigmoid(i)
        const float fv = rcp_f(1.0f + exp2_f(-g1));                       // sigmoid(f)
        const float gs = fmaf(-4.0f * LOG2E, rcp_f(1.0f + exp2_f(g2)),
                              2.0f * LOG2E);                              // 2L*tanh(g)
        const float ov = rcp_f(1.0f + exp2_f(-g3));                       // sigmoid(o)
        const float cn = fmaf(fv, cc, iv * gs);                           // c' = 2L*c
        cc = cn;
        const float th = fmaf(-2.0f, rcp_f(1.0f + exp2_f(cn)), 1.0f);     // tanh(c)
        *(_Float16*)(dl + woff) = (_Float16)(ov * th);                    // RTNE
    };

    // ---- prologue: phase A(0) — MFMA s0(0) against d_s0(-1)=0 ----
    MFMA_PH(xrd0, drS0, 0, A0a, A0b);
    __syncthreads();

#pragma unroll 1
    for (int t = 0; t < T_STEPS; ++t) {
        // phase B(t): MFMA s1(t)  ||  trans s0(t) -> write d_s0(t) rows 0-7
        MFMA_PH(xrd1, drS1, t, A1a, A1b);
        TRANS_WR(A0a, A0b, caccS0, woffS0);
        __syncthreads();

        // phase A(t+1): MFMA s0(t+1)  ||  trans s1(t) -> write d_s1(t) rows 8-15
        const int tn = (t + 1 < T_STEPS) ? (t + 1) : (T_STEPS - 1);
        MFMA_PH(xrd0, drS0, tn, A0a, A0b);   // t=511: harmless discard
        TRANS_WR(A1a, A1b, caccS1, woffS1);
        __syncthreads();
    }

    // ---- epilogue: h_T = Whr @ d(511); rows = batches 0-15; waves 0-3 ----
    if (wave < 4) {
        half8 aP[2];
        const int prow = wave * 16 + col;
#pragma unroll
        for (int ch = 0; ch < 2; ++ch)
#pragma unroll
            for (int j = 0; j < 8; ++j) {
                const int k = ch * 32 + quad * 8 + j;
                aP[ch][j] = (_Float16)((prow < NPROJ) ? Whr[prow * HID + k] : 0.0f);
            }

        half8 bd0, bd1;
        {
            const char* p0 = dl + col * ROWB + quad * 16;
            union { unsigned long long q[2]; half8 h; } u0, u1;
            u0.q[0] = *(const unsigned long long*)(p0);
            u0.q[1] = *(const unsigned long long*)(p0 + 8);
            u1.q[0] = *(const unsigned long long*)(p0 + 64);
            u1.q[1] = *(const unsigned long long*)(p0 + 72);
            bd0 = u0.h; bd1 = u1.h;
        }
        f32x4 hf = {0.f, 0.f, 0.f, 0.f};
        hf = __builtin_amdgcn_mfma_f32_16x16x32_f16(aP[0], bd0, hf, 0, 0, 0);
        hf = __builtin_amdgcn_mfma_f32_16x16x32_f16(aP[1], bd1, hf, 0, 0, 0);

        // store: p = wave*16 + quad*4 + r, batch = col  (wave 3: only quad 0 valid)
        const size_t bg = (size_t)blockIdx.x * NBATCH + col;
        float* o = out + bg * NPROJ;
        const int p0 = wave * 16 + quad * 4;
#pragma unroll
        for (int r = 0; r < 4; ++r) {
            const int p = p0 + r;
            if (p < NPROJ) o[p] = hf[r];
        }
    }
}

extern "C" void kernel_launch(void* const* d_in, const int* in_sizes, int n_in,
                              void* d_out, int out_size, void* d_ws, size_t ws_size,
                              hipStream_t stream) {
    const float* x   = (const float*)d_in[0];
    const float* Wih = (const float*)d_in[1];
    const float* Whh = (const float*)d_in[2];
    const float* bih = (const float*)d_in[3];
    const float* bhh = (const float*)d_in[4];
    const float* Whr = (const float*)d_in[5];
    float* out = (float*)d_out;

    dim3 grid(4096 / NBATCH);   // 256 blocks, 1 per CU
    dim3 block(512);            // 8 waves, 2 waves/SIMD
    lstmp_kernel<<<grid, block, 0, stream>>>(x, Wih, Whh, bih, bhh, Whr, out);
}

// Round 7
// 369.551 us; speedup vs baseline: 1.0587x; 1.0587x over previous
//
#include <hip/hip_runtime.h>

// LSTMP via MFMA, fp32 I/O, f16 compute, fp32 accumulate.
// B=4096, T=512, IN=4, HID=64, PROJ=52. Grid 256 x 512thr (8 waves, 2/SIMD),
// 16 batch/block.
//
// Round-19 = Round-18 two-stream pipeline with the PHASE ORDER FIXED.
// R18 regressed (363us) because each phase was {reads -> waitcnt -> MFMA}
// then TRANS: the wave stalled at the lgkm drain with the independent trans
// block stuck BEHIND the MFMAs in program order. R19 phase order:
//   1. issue LDS reads (x_next, d_next)          [no wait]
//   2. TRANS stream-prev + d-write               [covers read latency]
//   3. sched_barrier(0)                          [pin: no MFMA hoist]
//   4. bx assemble, xb-MFMA, M0-MFMA, M1-MFMA    [waitcnt lands here]
//   5. __syncthreads
// Streams: s0 = batches 0-7 (d rows 0-7), s1 = batches 8-15 (rows 8-15),
// phase-offset half a step; single d buffer; B-frag cols 8-15 mirror 0-7
// and lane col>=8 selects tile1's accumulator (per-cell gate packing as
// R16: tile row = 4*hloc+gate -> lane's f32x4 = [i,f,g,o] of one cell).
// Per-output accumulate order (xb seed, M0, M1), scales, f16 RTNE identical
// to R12..R18 -> absmax exactly 9.765625e-4 (R18 verified these numerics).
//   gates = (Whh@Whr)@d + [Wih|b]@[x;1]   (M precomputed per block, fp32)
// x staged to LDS as f16 once; log2e folded (i,f,o rows xL; g rows x2L;
// c' = 2L*c); h only in epilogue (Whr@d_T).

#define T_STEPS 512
#define HID 64
#define NPROJ 52
#define NBATCH 16
#define ROWB 136
#define DBYTES (NBATCH * ROWB)     // 2176 B, single buffer (rows=batch)
#define XBYTES (T_STEPS * 128)     // 65536 B: x_lds[t][b] 8B cells (4 x f16)
#define LOG2E 1.44269504088896340736f

typedef _Float16 half8 __attribute__((ext_vector_type(8)));
typedef float f32x4 __attribute__((ext_vector_type(4)));

__device__ __forceinline__ float exp2_f(float x) {
#if __has_builtin(__builtin_amdgcn_exp2f)
    return __builtin_amdgcn_exp2f(x);
#else
    return exp2f(x);
#endif
}
__device__ __forceinline__ float rcp_f(float x) {
    return __builtin_amdgcn_rcpf(x);
}

__global__ __launch_bounds__(512, 2)
void lstmp_kernel(const float* __restrict__ x,      // [4096][512][4]
                  const float* __restrict__ Wih,    // [256][4]
                  const float* __restrict__ Whh,    // [256][52]
                  const float* __restrict__ bih,    // [256]
                  const float* __restrict__ bhh,    // [256]
                  const float* __restrict__ Whr,    // [52][64]
                  float* __restrict__ out)          // [4096][52]
{
    __shared__ char lds[XBYTES + DBYTES];
    char* xl = lds;                 // x_lds: [t][b] 8B cells
    char* dl = lds + XBYTES;        // single d buffer, [16 batch][136B]

    const int tid  = threadIdx.x;
    const int lane = tid & 63;
    const int wave = tid >> 6;           // 0..7, owns hid block [8w, 8w+8)
    const int quad = lane >> 4;
    const int col  = lane & 15;
    const int bloc = col & 7;            // batch-in-stream
    const bool hi  = (col & 8) != 0;     // lane uses tile1's acc

    // ---- zero d buffer (t=0 phases read zeros as d(-1)) ----
    {
        unsigned* p = (unsigned*)dl;
        for (int i = tid; i < (int)(DBYTES / 4); i += 512) p[i] = 0u;
    }

    // ---- stage x -> LDS as f16 (one-time; coalesced global reads) ----
    {
        const float4* xg = (const float4*)x + (size_t)blockIdx.x * NBATCH * T_STEPS;
        for (int i = tid; i < NBATCH * T_STEPS; i += 512) {
            const int b = i >> 9;          // global layout is b-major
            const int t = i & (T_STEPS - 1);
            const float4 v = xg[i];
            union { _Float16 h[4]; unsigned long long q; } u;
            u.h[0] = (_Float16)v.x; u.h[1] = (_Float16)v.y;
            u.h[2] = (_Float16)v.z; u.h[3] = (_Float16)v.w;
            *(unsigned long long*)(xl + t * 128 + b * 8) = u.q;
        }
    }

    // ---- A-frag rows: tile row r = 4*hloc + gate (per-cell interleave) ----
    const int gate = col & 3;
    const int hl   = col >> 2;
    int rowT[2];
    rowT[0] = gate * HID + wave * 8 + hl;   // tile0: hid 8w+hl
    rowT[1] = rowT[0] + 4;                  // tile1: hid 8w+4+hl

    // ---- one-time: M = Whh @ Whr for the 2 packed rows (fp32) ----
    float macc[2][16];
#pragma unroll
    for (int g = 0; g < 2; ++g)
#pragma unroll
        for (int kk = 0; kk < 16; ++kk) macc[g][kk] = 0.0f;

    for (int p = 0; p < NPROJ; ++p) {
        const float w0 = Whh[rowT[0] * NPROJ + p];
        const float w1 = Whh[rowT[1] * NPROJ + p];
        const float* wr = Whr + p * HID + quad * 8;
        const float4 r0 = *(const float4*)(wr);
        const float4 r1 = *(const float4*)(wr + 4);
        const float4 r2 = *(const float4*)(wr + 32);
        const float4 r3 = *(const float4*)(wr + 36);
        const float rk[16] = {r0.x, r0.y, r0.z, r0.w, r1.x, r1.y, r1.z, r1.w,
                              r2.x, r2.y, r2.z, r2.w, r3.x, r3.y, r3.z, r3.w};
#pragma unroll
        for (int kk = 0; kk < 16; ++kk) {
            macc[0][kk] = fmaf(w0, rk[kk], macc[0][kk]);
            macc[1][kk] = fmaf(w1, rk[kk], macc[1][kk]);
        }
    }

    // ---- fold log2e, convert to f16 A-frags ----
    const float sc = (gate == 2) ? (2.0f * LOG2E) : LOG2E;   // g rows x2L
    half8 aM[2][2];   // [tile][K-chunk] (shared by both streams)
    half8 aXB[2];     // [Wih | bias] part, K=32 (quad0: k<4 = x, k==4 = 1-col)
#pragma unroll
    for (int g = 0; g < 2; ++g) {
#pragma unroll
        for (int ch = 0; ch < 2; ++ch)
#pragma unroll
            for (int j = 0; j < 8; ++j)
                aM[g][ch][j] = (_Float16)(macc[g][ch * 8 + j] * sc);
#pragma unroll
        for (int j = 0; j < 8; ++j) {
            const int k = quad * 8 + j;
            float v = 0.0f;
            if (k < 4)       v = Wih[rowT[g] * 4 + k];
            else if (k == 4) v = bih[rowT[g]] + bhh[rowT[g]];
            aXB[g][j] = (_Float16)(v * sc);
        }
    }

    float caccS0 = 0.0f, caccS1 = 0.0f;   // c' = 2L*c, 1 cell/lane/stream

    // lane's cell: hid = 8w + quad + 4*hi, batch = stream_base + bloc
    const int myhid  = wave * 8 + quad + (hi ? 4 : 0);
    const int woffS0 = bloc * ROWB + myhid * 2;            // d_s0 write (b16)
    const int woffS1 = (8 + bloc) * ROWB + myhid * 2;      // d_s1 write
    const int drS0   = bloc * ROWB + quad * 16;            // d_s0 read base
    const int drS1   = (8 + bloc) * ROWB + quad * 16;      // d_s1 read base
    const char* xrd0 = xl + bloc * 8;                      // x, stream 0
    const char* xrd1 = xl + (8 + bloc) * 8;                // x, stream 1

    __syncthreads();   // staging + zeros visible

    const f32x4 z = {0.f, 0.f, 0.f, 0.f};
    f32x4 A0a, A0b, A1a, A1b;   // per-stream gate accs (tile0, tile1)

    // trans + d write for one stream (registers from previous phase).
    auto TRANS_WR = [&](const f32x4& Pa, const f32x4& Pb, float& cc, int woff) {
        const float g0 = hi ? Pb[0] : Pa[0];
        const float g1 = hi ? Pb[1] : Pa[1];
        const float g2 = hi ? Pb[2] : Pa[2];
        const float g3 = hi ? Pb[3] : Pa[3];
        const float iv = rcp_f(1.0f + exp2_f(-g0));                       // sigmoid(i)
        const float fv = rcp_f(1.0f + exp2_f(-g1));                       // sigmoid(f)
        const float gs = fmaf(-4.0f * LOG2E, rcp_f(1.0f + exp2_f(g2)),
                              2.0f * LOG2E);                              // 2L*tanh(g)
        const float ov = rcp_f(1.0f + exp2_f(-g3));                       // sigmoid(o)
        const float cn = fmaf(fv, cc, iv * gs);                           // c' = 2L*c
        cc = cn;
        const float th = fmaf(-2.0f, rcp_f(1.0f + exp2_f(cn)), 1.0f);     // tanh(c)
        *(_Float16*)(dl + woff) = (_Float16)(ov * th);                    // RTNE
    };

    // ---- prologue: MFMA s0(0) against d_s0(-1)=0 (no trans yet) ----
    {
        union { unsigned long long q; _Float16 h[4]; } xu;
        xu.q = (quad == 0) ? *(const unsigned long long*)(xrd0 + 0 * 128) : 0ull;
        const char* p0 = dl + drS0;
        union { unsigned long long q[2]; half8 h; } u0, u1;
        u0.q[0] = *(const unsigned long long*)(p0);
        u0.q[1] = *(const unsigned long long*)(p0 + 8);
        u1.q[0] = *(const unsigned long long*)(p0 + 64);
        u1.q[1] = *(const unsigned long long*)(p0 + 72);
        half8 bx;
#pragma unroll
        for (int j = 0; j < 8; ++j) bx[j] = (_Float16)0.0f;
        if (quad == 0) {
            bx[0] = xu.h[0]; bx[1] = xu.h[1]; bx[2] = xu.h[2]; bx[3] = xu.h[3];
            bx[4] = (_Float16)1.0f;
        }
        A0a = __builtin_amdgcn_mfma_f32_16x16x32_f16(aXB[0], bx, z, 0, 0, 0);
        A0b = __builtin_amdgcn_mfma_f32_16x16x32_f16(aXB[1], bx, z, 0, 0, 0);
        A0a = __builtin_amdgcn_mfma_f32_16x16x32_f16(aM[0][0], u0.h, A0a, 0, 0, 0);
        A0b = __builtin_amdgcn_mfma_f32_16x16x32_f16(aM[1][0], u0.h, A0b, 0, 0, 0);
        A0a = __builtin_amdgcn_mfma_f32_16x16x32_f16(aM[0][1], u1.h, A0a, 0, 0, 0);
        A0b = __builtin_amdgcn_mfma_f32_16x16x32_f16(aM[1][1], u1.h, A0b, 0, 0, 0);
    }
    __syncthreads();

#pragma unroll 1
    for (int t = 0; t < T_STEPS; ++t) {
        // ======== phase B: finish s0(t) || start s1(t) ========
        {
            // 1. issue LDS reads: x_s1(t), d_s1(t-1) rows 8-15
            union { unsigned long long q; _Float16 h[4]; } xu;
            xu.q = (quad == 0) ? *(const unsigned long long*)(xrd1 + t * 128) : 0ull;
            const char* p0 = dl + drS1;
            union { unsigned long long q[2]; half8 h; } u0, u1;
            u0.q[0] = *(const unsigned long long*)(p0);
            u0.q[1] = *(const unsigned long long*)(p0 + 8);
            u1.q[0] = *(const unsigned long long*)(p0 + 64);
            u1.q[1] = *(const unsigned long long*)(p0 + 72);

            // 2. trans s0(t) -> write d_s0(t) rows 0-7 (covers read latency)
            TRANS_WR(A0a, A0b, caccS0, woffS0);

            // 3. keep MFMAs (and their waitcnt) below the trans block
            __builtin_amdgcn_sched_barrier(0);

            // 4. gates_s1(t) = xb + M@d  (accumulate order: xb, M0, M1)
            half8 bx;
#pragma unroll
            for (int j = 0; j < 8; ++j) bx[j] = (_Float16)0.0f;
            if (quad == 0) {
                bx[0] = xu.h[0]; bx[1] = xu.h[1]; bx[2] = xu.h[2]; bx[3] = xu.h[3];
                bx[4] = (_Float16)1.0f;
            }
            A1a = __builtin_amdgcn_mfma_f32_16x16x32_f16(aXB[0], bx, z, 0, 0, 0);
            A1b = __builtin_amdgcn_mfma_f32_16x16x32_f16(aXB[1], bx, z, 0, 0, 0);
            A1a = __builtin_amdgcn_mfma_f32_16x16x32_f16(aM[0][0], u0.h, A1a, 0, 0, 0);
            A1b = __builtin_amdgcn_mfma_f32_16x16x32_f16(aM[1][0], u0.h, A1b, 0, 0, 0);
            A1a = __builtin_amdgcn_mfma_f32_16x16x32_f16(aM[0][1], u1.h, A1a, 0, 0, 0);
            A1b = __builtin_amdgcn_mfma_f32_16x16x32_f16(aM[1][1], u1.h, A1b, 0, 0, 0);
        }
        __syncthreads();

        // ======== phase A: finish s1(t) || start s0(t+1) ========
        {
            const int tn = (t + 1 < T_STEPS) ? (t + 1) : (T_STEPS - 1);
            // 1. issue LDS reads: x_s0(t+1), d_s0(t) rows 0-7
            union { unsigned long long q; _Float16 h[4]; } xu;
            xu.q = (quad == 0) ? *(const unsigned long long*)(xrd0 + tn * 128) : 0ull;
            const char* p0 = dl + drS0;
            union { unsigned long long q[2]; half8 h; } u0, u1;
            u0.q[0] = *(const unsigned long long*)(p0);
            u0.q[1] = *(const unsigned long long*)(p0 + 8);
            u1.q[0] = *(const unsigned long long*)(p0 + 64);
            u1.q[1] = *(const unsigned long long*)(p0 + 72);

            // 2. trans s1(t) -> write d_s1(t) rows 8-15
            TRANS_WR(A1a, A1b, caccS1, woffS1);

            // 3. fence
            __builtin_amdgcn_sched_barrier(0);

            // 4. gates_s0(t+1) (t=511: harmless discard)
            half8 bx;
#pragma unroll
            for (int j = 0; j < 8; ++j) bx[j] = (_Float16)0.0f;
            if (quad == 0) {
                bx[0] = xu.h[0]; bx[1] = xu.h[1]; bx[2] = xu.h[2]; bx[3] = xu.h[3];
                bx[4] = (_Float16)1.0f;
            }
            A0a = __builtin_amdgcn_mfma_f32_16x16x32_f16(aXB[0], bx, z, 0, 0, 0);
            A0b = __builtin_amdgcn_mfma_f32_16x16x32_f16(aXB[1], bx, z, 0, 0, 0);
            A0a = __builtin_amdgcn_mfma_f32_16x16x32_f16(aM[0][0], u0.h, A0a, 0, 0, 0);
            A0b = __builtin_amdgcn_mfma_f32_16x16x32_f16(aM[1][0], u0.h, A0b, 0, 0, 0);
            A0a = __builtin_amdgcn_mfma_f32_16x16x32_f16(aM[0][1], u1.h, A0a, 0, 0, 0);
            A0b = __builtin_amdgcn_mfma_f32_16x16x32_f16(aM[1][1], u1.h, A0b, 0, 0, 0);
        }
        __syncthreads();
    }

    // ---- epilogue: h_T = Whr @ d(511); rows = batches 0-15; waves 0-3 ----
    if (wave < 4) {
        half8 aP[2];
        const int prow = wave * 16 + col;
#pragma unroll
        for (int ch = 0; ch < 2; ++ch)
#pragma unroll
            for (int j = 0; j < 8; ++j) {
                const int k = ch * 32 + quad * 8 + j;
                aP[ch][j] = (_Float16)((prow < NPROJ) ? Whr[prow * HID + k] : 0.0f);
            }

        half8 bd0, bd1;
        {
            const char* p0 = dl + col * ROWB + quad * 16;
            union { unsigned long long q[2]; half8 h; } u0, u1;
            u0.q[0] = *(const unsigned long long*)(p0);
            u0.q[1] = *(const unsigned long long*)(p0 + 8);
            u1.q[0] = *(const unsigned long long*)(p0 + 64);
            u1.q[1] = *(const unsigned long long*)(p0 + 72);
            bd0 = u0.h; bd1 = u1.h;
        }
        f32x4 hf = {0.f, 0.f, 0.f, 0.f};
        hf = __builtin_amdgcn_mfma_f32_16x16x32_f16(aP[0], bd0, hf, 0, 0, 0);
        hf = __builtin_amdgcn_mfma_f32_16x16x32_f16(aP[1], bd1, hf, 0, 0, 0);

        // store: p = wave*16 + quad*4 + r, batch = col  (wave 3: only quad 0 valid)
        const size_t bg = (size_t)blockIdx.x * NBATCH + col;
        float* o = out + bg * NPROJ;
        const int p0 = wave * 16 + quad * 4;
#pragma unroll
        for (int r = 0; r < 4; ++r) {
            const int p = p0 + r;
            if (p < NPROJ) o[p] = hf[r];
        }
    }
}

extern "C" void kernel_launch(void* const* d_in, const int* in_sizes, int n_in,
                              void* d_out, int out_size, void* d_ws, size_t ws_size,
                              hipStream_t stream) {
    const float* x   = (const float*)d_in[0];
    const float* Wih = (const float*)d_in[1];
    const float* Whh = (const float*)d_in[2];
    const float* bih = (const float*)d_in[3];
    const float* bhh = (const float*)d_in[4];
    const float* Whr = (const float*)d_in[5];
    float* out = (float*)d_out;

    dim3 grid(4096 / NBATCH);   // 256 blocks, 1 per CU
    dim3 block(512);            // 8 waves, 2 waves/SIMD
    lstmp_kernel<<<grid, block, 0, stream>>>(x, Wih, Whh, bih, bhh, Whr, out);
}